// Round 2
// baseline (192.988 us; speedup 1.0000x reference)
//
#include <hip/hip_runtime.h>
#include <stdint.h>
#include <float.h>

#define TOTAL 16368
#define KSEL 500
#define QCAP0 384         // per-quarter cap, g0/g1 (mean ~278-281, +6.8 sd)
#define QCAP2 224         // per-quarter cap, g2 (mean ~158, +6.3 sd)
#define NBUCKET 64

// order-preserving float<->uint key (monotonic increasing on finite floats)
__device__ __forceinline__ uint32_t fkey(float f) {
    uint32_t u = __float_as_uint(f);
    return (u & 0x80000000u) ? ~u : (u | 0x80000000u);
}
__device__ __forceinline__ float keyf(uint32_t k) {
    uint32_t u = (k & 0x80000000u) ? (k & 0x7FFFFFFFu) : ~k;
    return __uint_as_float(u);
}
__device__ __forceinline__ int wave_sumi(int v) {
    #pragma unroll
    for (int o = 32; o > 0; o >>= 1) v += __shfl_xor(v, o, 64);
    return v;
}
__device__ __forceinline__ float wave_sumf(float v) {
    #pragma unroll
    for (int o = 32; o > 0; o >>= 1) v += __shfl_xor(v, o, 64);
    return v;
}
__device__ __forceinline__ float wave_maxf(float v) {
    #pragma unroll
    for (int o = 32; o > 0; o >>= 1) v = fmaxf(v, __shfl_xor(v, o, 64));
    return v;
}
__device__ __forceinline__ void lse_merge(float& m, float& l, float m2, float l2) {
    float M = fmaxf(m, m2);
    l = l * __expf(m - M) + l2 * __expf(m2 - M);
    m = M;
}

// exact exhaustive fallback (never taken for N(0,1) bench data); returns kl on
// lane 0 (0 elsewhere). Bisection on 45-bit key (fkey<<13 | (8191-idx)).
__device__ __noinline__ float wave_slow_kl(const float* __restrict__ t,
                                           const float* __restrict__ s, int C) {
    const int lane = threadIdx.x & 63;
    uint64_t lo = 0ull, hi = (1ull << 45), tau = 0ull;
    int cl = C, ch = 0;
    for (int it = 0; it < 100; ++it) {
        uint64_t span = hi - lo;
        if (span <= 1ull) { tau = lo; break; }
        uint64_t mid;
        if (it & 1) mid = lo + (span >> 1);
        else {
            uint64_t st = span * (uint64_t)(cl - KSEL) / (uint64_t)(cl - ch);
            if (st < 1) st = 1;
            if (st > span - 1) st = span - 1;
            mid = lo + st;
        }
        int c = 0;
        for (int i = lane; i < C; i += 64) {
            uint64_t ck = ((uint64_t)fkey(t[i]) << 13) | (uint64_t)(8191 - i);
            c += (ck > mid);
        }
        c = wave_sumi(c);
        if (c == KSEL) { tau = mid; break; }
        if (c > KSEL) { lo = mid; cl = c; } else { hi = mid; ch = c; }
    }
    float tmx = -FLT_MAX;
    for (int i = lane; i < C; i += 64) tmx = fmaxf(tmx, t[i]);
    tmx = wave_maxf(tmx);
    float St = 0.f, Stt = 0.f, Sts = 0.f, sm = -FLT_MAX;
    for (int i = lane; i < C; i += 64) {
        float x = t[i];
        uint64_t ck = ((uint64_t)fkey(x) << 13) | (uint64_t)(8191 - i);
        if (ck > tau) {
            float e = __expf(x - tmx), v = s[i];
            St += e; Stt += e * x; Sts += e * v;
            sm = fmaxf(sm, v);
        }
    }
    St = wave_sumf(St); Stt = wave_sumf(Stt); Sts = wave_sumf(Sts); sm = wave_maxf(sm);
    float Ss = 0.f;
    for (int i = lane; i < C; i += 64) {
        uint64_t ck = ((uint64_t)fkey(t[i]) << 13) | (uint64_t)(8191 - i);
        if (ck > tau) Ss += __expf(s[i] - sm);
    }
    Ss = wave_sumf(Ss);
    if (lane == 0)
        return (Stt - Sts) / St - tmx - __logf(St) + sm + __logf(Ss);
    return 0.f;
}

// One wave compacts its NF4Q*256-float quarter of a group: threshold filter ->
// wave exclusive scan -> scatter (key, student val, global idx) into this
// wave's PRIVATE SEGCAP-slot segment of the shared candidate arrays. Unused
// tail slots are key-zeroed (key 0 can never be selected: valid keys have the
// sign bit set since thr > 0). Returns this quarter's count.
template <int NF4Q, int SEGCAP>
__device__ int quarter_compact(const float* __restrict__ tq,
                               const float* __restrict__ sq,
                               float thr, int idx_off,
                               uint32_t* kv, float* sv, uint16_t* ix) {
    const int lane = threadIdx.x & 63;
    const float4* t4 = (const float4*)tq;
    float4 buf[NF4Q];
    #pragma unroll
    for (int u = 0; u < NF4Q; ++u) buf[u] = t4[u * 64 + lane];
    int myc = 0;
    #pragma unroll
    for (int u = 0; u < NF4Q; ++u)
        myc += (buf[u].x > thr) + (buf[u].y > thr) +
               (buf[u].z > thr) + (buf[u].w > thr);
    int inc = myc;
    #pragma unroll
    for (int o = 1; o < 64; o <<= 1) {
        int y = __shfl_up(inc, o, 64);
        if (lane >= o) inc += y;
    }
    int base = inc - myc;
    int total = __shfl(inc, 63, 64);
    if (total <= SEGCAP) {
        #pragma unroll
        for (int u = 0; u < NF4Q; ++u) {
            float xs[4] = {buf[u].x, buf[u].y, buf[u].z, buf[u].w};
            #pragma unroll
            for (int q = 0; q < 4; ++q) {
                if (xs[q] > thr) {
                    int gi = ((u * 64 + lane) << 2) + q;
                    kv[base] = fkey(xs[q]);
                    sv[base] = sq[gi];                    // student gather (spread across waves)
                    ix[base] = (uint16_t)(gi + idx_off);  // global group index for tie-break
                    ++base;
                }
            }
        }
        for (int p = total + lane; p < SEGCAP; p += 64) kv[p] = 0u;  // pad invalid slots
    }
    return total;
}

// Exact top-KSEL + KL over the 4-segment LDS candidate array (keys to regs,
// student vals read from LDS on demand). Falls back to exhaustive scan on
// count overflow/underflow. Returns kl on lane 0.   NS == 4*SEGCAP/64.
template <int NS, int SEGCAP>
__device__ float seg_select(const uint32_t* __restrict__ kv,
                            const float* __restrict__ sv,
                            const uint16_t* __restrict__ ix,
                            const int* cnts, int C,
                            const float* __restrict__ tg,
                            const float* __restrict__ sg) {
    const int lane = threadIdx.x & 63;
    const int tot = cnts[0] + cnts[1] + cnts[2] + cnts[3];
    bool bad = (tot < KSEL) || (cnts[0] > SEGCAP) || (cnts[1] > SEGCAP) ||
               (cnts[2] > SEGCAP) || (cnts[3] > SEGCAP);
    if (bad) return wave_slow_kl(tg, sg, C);

    uint32_t key[NS];
    #pragma unroll
    for (int j = 0; j < NS; ++j) key[j] = kv[lane + j * 64];

    uint32_t kmx = 0u, kmn = 0xFFFFFFFFu;
    #pragma unroll
    for (int j = 0; j < NS; ++j) {
        uint32_t k = key[j];
        kmx = k > kmx ? k : kmx;
        if (k) kmn = k < kmn ? k : kmn;
    }
    #pragma unroll
    for (int o = 32; o > 0; o >>= 1) {
        uint32_t a = __shfl_xor(kmx, o, 64); kmx = a > kmx ? a : kmx;
        uint32_t b = __shfl_xor(kmn, o, 64); kmn = b < kmn ? b : kmn;
    }
    const float tmax = keyf(kmx);

    uint32_t lo = kmn - 1u, hi = kmx, tauhi = kmx;
    int cl = tot, ch = 0, cut = -1;
    bool exact = false;
    for (int it = 0; it < 80; ++it) {
        uint32_t span = hi - lo;
        if (span <= 1u) break;
        uint32_t mid;
        if (!(it & 1)) {  // false position on empirical CDF
            uint64_t st = (uint64_t)span * (uint32_t)(cl - KSEL) / (uint32_t)(cl - ch);
            if (st < 1) st = 1;
            if (st > span - 1) st = span - 1;
            mid = lo + (uint32_t)st;
        } else mid = lo + (span >> 1);
        int c = 0;
        #pragma unroll
        for (int j = 0; j < NS; ++j) c += (key[j] > mid);
        c = wave_sumi(c);
        if (c == KSEL) { tauhi = mid; exact = true; break; }
        if (c > KSEL) { lo = mid; cl = c; } else { hi = mid; ch = c; }
    }
    if (!exact) {
        tauhi = hi;
        const int nT = KSEL - ch, nTie = cl - ch;
        if (nT >= nTie) cut = 0x7FFFFFFF;
        else {  // lowest-index tie-break among key==tauhi (rare path)
            int l = -1, h = C - 1;
            while (h - l > 1) {
                int m = (l + h) >> 1;
                int c = 0;
                #pragma unroll
                for (int j = 0; j < NS; ++j)
                    c += (key[j] == tauhi && (int)ix[lane + j * 64] <= m);
                c = wave_sumi(c);
                if (c >= nT) h = m; else l = m;
            }
            cut = h;
        }
    }

    uint32_t selm = 0u;
    if (cut == -1) {
        #pragma unroll
        for (int j = 0; j < NS; ++j) selm |= (key[j] > tauhi ? 1u : 0u) << j;
    } else if (cut == 0x7FFFFFFF) {
        #pragma unroll
        for (int j = 0; j < NS; ++j) selm |= (key[j] >= tauhi ? 1u : 0u) << j;
    } else {
        #pragma unroll
        for (int j = 0; j < NS; ++j) {
            bool sj = (key[j] > tauhi) ||
                      (key[j] == tauhi && (int)ix[lane + j * 64] <= cut);
            selm |= (sj ? 1u : 0u) << j;
        }
    }

    float St = 0.f, Stt = 0.f, Sts = 0.f, sm = -FLT_MAX;
    #pragma unroll
    for (int j = 0; j < NS; ++j) {
        if (selm & (1u << j)) {
            float tv = keyf(key[j]);
            float e = __expf(tv - tmax);
            float s = sv[lane + j * 64];
            St += e; Stt += e * tv; Sts += e * s;
            sm = fmaxf(sm, s);
        }
    }
    #pragma unroll
    for (int o = 32; o > 0; o >>= 1) {
        St  += __shfl_xor(St,  o, 64);
        Stt += __shfl_xor(Stt, o, 64);
        Sts += __shfl_xor(Sts, o, 64);
        sm = fmaxf(sm, __shfl_xor(sm, o, 64));
    }
    float Ss = 0.f;
    #pragma unroll
    for (int j = 0; j < NS; ++j)
        if (selm & (1u << j)) Ss += __expf(sv[lane + j * 64] - sm);
    Ss = wave_sumf(Ss);
    if (lane == 0)
        return (Stt - Sts) / St - tmax - __logf(St) + sm + __logf(Ss);
    return 0.f;
}

// Exact top-KSEL + KL on dense register-resident keys (whole group in one wave).
template <int NS, class IdxF>
__device__ float select_accum(uint32_t (&key)[NS], IdxF idxOf, const float* svp) {
    const int lane = threadIdx.x & 63;
    uint32_t kmx = 0u, kmn = 0xFFFFFFFFu;
    #pragma unroll
    for (int j = 0; j < NS; ++j) {
        uint32_t k = key[j];
        kmx = k > kmx ? k : kmx;
        kmn = k < kmn ? k : kmn;
    }
    #pragma unroll
    for (int o = 32; o > 0; o >>= 1) {
        uint32_t a = __shfl_xor(kmx, o, 64); kmx = a > kmx ? a : kmx;
        uint32_t b = __shfl_xor(kmn, o, 64); kmn = b < kmn ? b : kmn;
    }
    const float tmax = keyf(kmx);

    uint32_t lo = kmn - 1u, hi = kmx, tauhi = kmx;
    int cl = NS * 64, ch = 0, cut = -1;
    bool exact = false;
    for (int it = 0; it < 80; ++it) {
        uint32_t span = hi - lo;
        if (span <= 1u) break;
        uint32_t mid;
        if (!(it & 1)) {
            uint64_t st = (uint64_t)span * (uint32_t)(cl - KSEL) / (uint32_t)(cl - ch);
            if (st < 1) st = 1;
            if (st > span - 1) st = span - 1;
            mid = lo + (uint32_t)st;
        } else mid = lo + (span >> 1);
        int c = 0;
        #pragma unroll
        for (int j = 0; j < NS; ++j) c += (key[j] > mid);
        c = wave_sumi(c);
        if (c == KSEL) { tauhi = mid; exact = true; break; }
        if (c > KSEL) { lo = mid; cl = c; } else { hi = mid; ch = c; }
    }
    if (!exact) {
        tauhi = hi;
        const int nT = KSEL - ch, nTie = cl - ch;
        if (nT >= nTie) cut = 0x7FFFFFFF;
        else {
            int l = -1, h = NS * 64 - 1;
            while (h - l > 1) {
                int m = (l + h) >> 1;
                int c = 0;
                #pragma unroll
                for (int j = 0; j < NS; ++j)
                    c += (key[j] == tauhi && idxOf(j) <= m);
                c = wave_sumi(c);
                if (c >= nT) h = m; else l = m;
            }
            cut = h;
        }
    }

    float St = 0.f, Stt = 0.f, Sts = 0.f, sm = -FLT_MAX;
    #pragma unroll
    for (int j = 0; j < NS; ++j) {
        uint32_t kj = key[j];
        bool sj = (kj > tauhi) || (kj == tauhi && idxOf(j) <= cut);
        if (sj) {
            float tv = keyf(kj);
            float e = __expf(tv - tmax);
            St += e; Stt += e * tv; Sts += e * svp[j];
            sm = fmaxf(sm, svp[j]);
        }
    }
    #pragma unroll
    for (int o = 32; o > 0; o >>= 1) {
        St  += __shfl_xor(St,  o, 64);
        Stt += __shfl_xor(Stt, o, 64);
        Sts += __shfl_xor(Sts, o, 64);
        sm = fmaxf(sm, __shfl_xor(sm, o, 64));
    }
    float Ss = 0.f;
    #pragma unroll
    for (int j = 0; j < NS; ++j) {
        uint32_t kj = key[j];
        bool sj = (kj > tauhi) || (kj == tauhi && idxOf(j) <= cut);
        if (sj) Ss += __expf(svp[j] - sm);
    }
    Ss = wave_sumf(Ss);
    if (lane == 0)
        return (Stt - Sts) / St - tmax - __logf(St) + sm + __logf(Ss);
    return 0.f;
}

// mid groups (C = NJ*64): whole group + student prefetched to registers
template <int NJ>
__device__ float mid_wave(const float* __restrict__ t, const float* __restrict__ s) {
    const int lane = threadIdx.x & 63;
    const float4* t4 = (const float4*)t;
    const float4* s4 = (const float4*)s;
    uint32_t key[NJ];
    float svp[NJ];
    #pragma unroll
    for (int c = 0; c < NJ / 4; ++c) {
        float4 x = t4[lane + c * 64];
        float4 y = s4[lane + c * 64];
        key[4 * c + 0] = fkey(x.x); key[4 * c + 1] = fkey(x.y);
        key[4 * c + 2] = fkey(x.z); key[4 * c + 3] = fkey(x.w);
        svp[4 * c + 0] = y.x; svp[4 * c + 1] = y.y;
        svp[4 * c + 2] = y.z; svp[4 * c + 3] = y.w;
    }
    auto idxOf = [&](int j) { return ((lane + (j >> 2) * 64) << 2) + (j & 3); };
    return select_accum<NJ>(key, idxOf, svp);
}

// tiny groups (k == C <= 256): whole-group softmax; returns kl on lane 0
__device__ float tiny_group(const float* __restrict__ t, const float* __restrict__ s,
                            int Cg) {
    const int lane = threadIdx.x & 63;
    float St = 0.f, Stt = 0.f, Sts = 0.f, m = -FLT_MAX, l = 0.f;
    float tv[4], svv[4];
    #pragma unroll
    for (int q = 0; q < 4; ++q) {
        int i = lane + q * 64;
        bool va = i < Cg;
        tv[q] = va ? t[i] : -FLT_MAX;
        svv[q] = va ? s[i] : 0.f;
    }
    float mx = -FLT_MAX;
    #pragma unroll
    for (int q = 0; q < 4; ++q) mx = fmaxf(mx, tv[q]);
    mx = wave_maxf(mx);
    #pragma unroll
    for (int q = 0; q < 4; ++q) {
        if (lane + q * 64 < Cg) {
            float e = __expf(tv[q] - mx);
            St += e; Stt += e * tv[q]; Sts += e * svv[q];
            float x = svv[q];
            if (x > m) { l = l * __expf(m - x) + 1.f; m = x; }
            else       { l += __expf(x - m); }
        }
    }
    #pragma unroll
    for (int o = 32; o > 0; o >>= 1) {
        St  += __shfl_xor(St,  o, 64);
        Stt += __shfl_xor(Stt, o, 64);
        Sts += __shfl_xor(Sts, o, 64);
        float m2 = __shfl_xor(m, o, 64);
        float l2 = __shfl_xor(l, o, 64);
        lse_merge(m, l, m2, l2);
    }
    if (lane == 0)
        return (Stt - Sts) / St - mx - __logf(St) + m + __logf(l);
    return 0.f;
}

// 256 threads = 4 waves, byte-BALANCED (~31 KB streamed+gathered per wave):
// Phase A: every wave compacts a quarter of g0 (thr 1.10) and g1 (thr 0.60);
//   g2 quarters (thr 0.50): w0->q0, w1->q1, w3->q2+q3 (w2 skips; it takes g3).
//   Extras: w0 +tinies, w1 +g4 (select in-reg), w2 +g3 (select in-reg).
// One __syncthreads, then Phase B (pure LDS/VALU selection, ~1 us each):
//   w3: select+KL g0   w0: select+KL g1   w1: select+KL g2   w2: idle.
__global__ __launch_bounds__(256, 4) void kd_all(const float* __restrict__ sL,
                                                 const float* __restrict__ tL,
                                                 float* __restrict__ partial) {
    __shared__ uint32_t kv0[4 * QCAP0];
    __shared__ float    sv0[4 * QCAP0];
    __shared__ uint16_t ix0[4 * QCAP0];
    __shared__ uint32_t kv1[4 * QCAP0];
    __shared__ float    sv1[4 * QCAP0];
    __shared__ uint16_t ix1[4 * QCAP0];
    __shared__ uint32_t kv2[4 * QCAP2];
    __shared__ float    sv2[4 * QCAP2];
    __shared__ uint16_t ix2[4 * QCAP2];
    __shared__ int      cnts[12];   // [0..3]=g0, [4..7]=g1, [8..11]=g2 quarters

    const int row = blockIdx.x;
    const int w = threadIdx.x >> 6;
    const int lane = threadIdx.x & 63;
    const float* tr = tL + (size_t)row * TOTAL;
    const float* sr = sL + (size_t)row * TOTAL;

    float kl = 0.f;

    // ---- Phase A: cooperative compaction + balanced register-resident groups
    int c0 = quarter_compact<8, QCAP0>(tr + w * 2048, sr + w * 2048, 1.10f,
                                       w * 2048,
                                       kv0 + w * QCAP0, sv0 + w * QCAP0,
                                       ix0 + w * QCAP0);
    int c1 = quarter_compact<4, QCAP0>(tr + 8192 + w * 1024, sr + 8192 + w * 1024,
                                       0.60f, w * 1024,
                                       kv1 + w * QCAP0, sv1 + w * QCAP0,
                                       ix1 + w * QCAP0);
    if (lane == 0) { cnts[w] = c0; cnts[4 + w] = c1; }

    if (w != 2) {
        int q = (w == 3) ? 2 : w;
        int c2 = quarter_compact<2, QCAP2>(tr + 12288 + q * 512, sr + 12288 + q * 512,
                                           0.50f, q * 512,
                                           kv2 + q * QCAP2, sv2 + q * QCAP2,
                                           ix2 + q * QCAP2);
        if (lane == 0) cnts[8 + q] = c2;
        if (w == 3) {
            int c3 = quarter_compact<2, QCAP2>(tr + 12288 + 3 * 512,
                                               sr + 12288 + 3 * 512,
                                               0.50f, 3 * 512,
                                               kv2 + 3 * QCAP2, sv2 + 3 * QCAP2,
                                               ix2 + 3 * QCAP2);
            if (lane == 0) cnts[11] = c3;
        }
    }

    switch (w) {
    case 0:
        kl += tiny_group(tr + 15872, sr + 15872, 256);
        kl += tiny_group(tr + 16128, sr + 16128, 128);
        kl += tiny_group(tr + 16256, sr + 16256, 64);
        kl += tiny_group(tr + 16320, sr + 16320, 32);
        kl += tiny_group(tr + 16352, sr + 16352, 16);
        break;
    case 1:
        kl += mid_wave<8>(tr + 15360, sr + 15360);    // g4, C=512 (top-500)
        break;
    case 2:
        kl += mid_wave<16>(tr + 14336, sr + 14336);   // g3, C=1024 (top-500)
        break;
    default:
        break;
    }

    __syncthreads();

    // ---- Phase B: selection over LDS candidates (no global loads) ----
    if (w == 3)
        kl += seg_select<24, QCAP0>(kv0, sv0, ix0, cnts, 8192, tr, sr);
    else if (w == 0)
        kl += seg_select<24, QCAP0>(kv1, sv1, ix1, cnts + 4, 4096,
                                    tr + 8192, sr + 8192);
    else if (w == 1)
        kl += seg_select<14, QCAP2>(kv2, sv2, ix2, cnts + 8, 2048,
                                    tr + 12288, sr + 12288);

    if (lane == 0)
        atomicAdd(&partial[(row + w * 37) & (NBUCKET - 1)], kl * (0.1f / 1024.f));
}

__global__ void zero_ws(float* partial) {
    if (threadIdx.x < NBUCKET) partial[threadIdx.x] = 0.f;
}

__global__ void final_sum(const float* __restrict__ partial, float* __restrict__ out) {
    float v = (threadIdx.x < NBUCKET) ? partial[threadIdx.x] : 0.f;
    #pragma unroll
    for (int o = 32; o > 0; o >>= 1) v += __shfl_down(v, o, 64);
    if (threadIdx.x == 0) out[0] = v;
}

extern "C" void kernel_launch(void* const* d_in, const int* in_sizes, int n_in,
                              void* d_out, int out_size, void* d_ws, size_t ws_size,
                              hipStream_t stream) {
    (void)in_sizes; (void)n_in; (void)ws_size; (void)out_size;
    const float* s = (const float*)d_in[0];
    const float* t = (const float*)d_in[1];
    float* out = (float*)d_out;
    float* ws = (float*)d_ws;

    hipLaunchKernelGGL(zero_ws, dim3(1), dim3(64), 0, stream, ws);
    hipLaunchKernelGGL(kd_all, dim3(1024), dim3(256), 0, stream, s, t, ws);
    hipLaunchKernelGGL(final_sum, dim3(1), dim3(64), 0, stream, ws, out);
}

// Round 4
// 188.031 us; speedup vs baseline: 1.0264x; 1.0264x over previous
//
#include <hip/hip_runtime.h>
#include <stdint.h>
#include <float.h>

#define TOTAL 16368
#define KSEL 500
#define CAP 1280          // candidate cap for g1 big_wave (mean ~1123, +5.5 sd)
#define NSLOT 20          // CAP / 64
#define HCAP 672          // per-half candidate cap for g0 (mean ~556, +5.3 sd)
#define NSEG 21           // 2*HCAP/64
#define NBUCKET 64

// order-preserving float<->uint key (monotonic increasing on finite floats)
__device__ __forceinline__ uint32_t fkey(float f) {
    uint32_t u = __float_as_uint(f);
    return (u & 0x80000000u) ? ~u : (u | 0x80000000u);
}
__device__ __forceinline__ float keyf(uint32_t k) {
    uint32_t u = (k & 0x80000000u) ? (k & 0x7FFFFFFFu) : ~k;
    return __uint_as_float(u);
}
__device__ __forceinline__ int wave_sumi(int v) {
    #pragma unroll
    for (int o = 32; o > 0; o >>= 1) v += __shfl_xor(v, o, 64);
    return v;
}
__device__ __forceinline__ float wave_sumf(float v) {
    #pragma unroll
    for (int o = 32; o > 0; o >>= 1) v += __shfl_xor(v, o, 64);
    return v;
}
__device__ __forceinline__ float wave_maxf(float v) {
    #pragma unroll
    for (int o = 32; o > 0; o >>= 1) v = fmaxf(v, __shfl_xor(v, o, 64));
    return v;
}
__device__ __forceinline__ void lse_merge(float& m, float& l, float m2, float l2) {
    float M = fmaxf(m, m2);
    l = l * __expf(m - M) + l2 * __expf(m2 - M);
    m = M;
}

// exact exhaustive fallback (never taken for N(0,1) bench data); returns kl on
// lane 0 (0 elsewhere). Bisection on 45-bit key (fkey<<13 | (8191-idx)).
__device__ __noinline__ float wave_slow_kl(const float* __restrict__ t,
                                           const float* __restrict__ s, int C) {
    const int lane = threadIdx.x & 63;
    uint64_t lo = 0ull, hi = (1ull << 45), tau = 0ull;
    int cl = C, ch = 0;
    for (int it = 0; it < 100; ++it) {
        uint64_t span = hi - lo;
        if (span <= 1ull) { tau = lo; break; }
        uint64_t mid;
        if (it & 1) mid = lo + (span >> 1);
        else {
            uint64_t st = span * (uint64_t)(cl - KSEL) / (uint64_t)(cl - ch);
            if (st < 1) st = 1;
            if (st > span - 1) st = span - 1;
            mid = lo + st;
        }
        int c = 0;
        for (int i = lane; i < C; i += 64) {
            uint64_t ck = ((uint64_t)fkey(t[i]) << 13) | (uint64_t)(8191 - i);
            c += (ck > mid);
        }
        c = wave_sumi(c);
        if (c == KSEL) { tau = mid; break; }
        if (c > KSEL) { lo = mid; cl = c; } else { hi = mid; ch = c; }
    }
    float tmx = -FLT_MAX;
    for (int i = lane; i < C; i += 64) tmx = fmaxf(tmx, t[i]);
    tmx = wave_maxf(tmx);
    float St = 0.f, Stt = 0.f, Sts = 0.f, sm = -FLT_MAX;
    for (int i = lane; i < C; i += 64) {
        float x = t[i];
        uint64_t ck = ((uint64_t)fkey(x) << 13) | (uint64_t)(8191 - i);
        if (ck > tau) {
            float e = __expf(x - tmx), v = s[i];
            St += e; Stt += e * x; Sts += e * v;
            sm = fmaxf(sm, v);
        }
    }
    St = wave_sumf(St); Stt = wave_sumf(Stt); Sts = wave_sumf(Sts); sm = wave_maxf(sm);
    float Ss = 0.f;
    for (int i = lane; i < C; i += 64) {
        uint64_t ck = ((uint64_t)fkey(t[i]) << 13) | (uint64_t)(8191 - i);
        if (ck > tau) Ss += __expf(s[i] - sm);
    }
    Ss = wave_sumf(Ss);
    if (lane == 0)
        return (Stt - Sts) / St - tmx - __logf(St) + sm + __logf(Ss);
    return 0.f;
}

// PROVEN round-0 path: big group handled start-to-finish by ONE wave
// (C = NF4*256): stream in 8-float4 bursts; scan-based compaction to LDS;
// keys to regs; EARLY candidate student gather (outstanding across bisection);
// exact bisection + rare LDS-idx tie-break. Returns kl on lane 0.
template <int NF4>
__device__ float big_wave(const float* __restrict__ tg, const float* __restrict__ s,
                          float thr, float* vals, uint16_t* idxs) {
    const int lane = threadIdx.x & 63;
    const float4* t4 = (const float4*)tg;
    int cnt = 0;
    #pragma unroll
    for (int c0 = 0; c0 < NF4; c0 += 8) {
        float4 buf[8];
        #pragma unroll
        for (int u = 0; u < 8; ++u) buf[u] = t4[(c0 + u) * 64 + lane];
        int myc = 0;
        #pragma unroll
        for (int u = 0; u < 8; ++u)
            myc += (buf[u].x > thr) + (buf[u].y > thr) +
                   (buf[u].z > thr) + (buf[u].w > thr);
        int inc = myc;
        #pragma unroll
        for (int o = 1; o < 64; o <<= 1) {
            int y = __shfl_up(inc, o, 64);
            if (lane >= o) inc += y;
        }
        int base = cnt + inc - myc;
        cnt += __shfl(inc, 63, 64);
        #pragma unroll
        for (int u = 0; u < 8; ++u) {
            float xs[4] = {buf[u].x, buf[u].y, buf[u].z, buf[u].w};
            #pragma unroll
            for (int q = 0; q < 4; ++q) {
                if (xs[q] > thr) {
                    if (base < CAP) {
                        vals[base] = xs[q];
                        idxs[base] = (uint16_t)((((c0 + u) * 64 + lane) << 2) + q);
                    }
                    ++base;
                }
            }
        }
    }
    if (cnt < KSEL || cnt > CAP) return wave_slow_kl(tg, s, NF4 * 256);

    // keys to regs + EARLY student gather (vmcnt loads drain under bisection)
    uint32_t key[NSLOT];
    float svc[NSLOT];
    #pragma unroll
    for (int j = 0; j < NSLOT; ++j) {
        int p = lane + j * 64;
        bool v = p < cnt;
        key[j] = v ? fkey(vals[p]) : 0u;
        svc[j] = v ? s[(int)idxs[p]] : 0.f;
    }
    uint32_t kmx = 0u, kmn = 0xFFFFFFFFu;
    #pragma unroll
    for (int j = 0; j < NSLOT; ++j) {
        uint32_t k = key[j];
        kmx = k > kmx ? k : kmx;
        if (k) kmn = k < kmn ? k : kmn;
    }
    #pragma unroll
    for (int o = 32; o > 0; o >>= 1) {
        uint32_t a = __shfl_xor(kmx, o, 64); kmx = a > kmx ? a : kmx;
        uint32_t b = __shfl_xor(kmn, o, 64); kmn = b < kmn ? b : kmn;
    }
    const float tmax = keyf(kmx);

    uint32_t lo = kmn - 1u, hi = kmx, tauhi = kmx;
    int cl = cnt, ch = 0, cut = -1;
    bool exact = false;
    for (int it = 0; it < 80; ++it) {
        uint32_t span = hi - lo;
        if (span <= 1u) break;
        uint32_t mid;
        if (!(it & 1)) {  // false position on empirical CDF
            uint64_t st = (uint64_t)span * (uint32_t)(cl - KSEL) / (uint32_t)(cl - ch);
            if (st < 1) st = 1;
            if (st > span - 1) st = span - 1;
            mid = lo + (uint32_t)st;
        } else mid = lo + (span >> 1);
        int c = 0;
        #pragma unroll
        for (int j = 0; j < NSLOT; ++j) c += (key[j] > mid);
        c = wave_sumi(c);
        if (c == KSEL) { tauhi = mid; exact = true; break; }
        if (c > KSEL) { lo = mid; cl = c; } else { hi = mid; ch = c; }
    }
    if (!exact) {
        tauhi = hi;
        const int nT = KSEL - ch, nTie = cl - ch;
        if (nT >= nTie) cut = 0x7FFFFFFF;
        else {  // lowest-index tie-break; idx re-read from LDS (rare path)
            int l = -1, h = 8191;
            while (h - l > 1) {
                int m = (l + h) >> 1;
                int c = 0;
                #pragma unroll
                for (int j = 0; j < NSLOT; ++j) {
                    int p = lane + j * 64;
                    c += (key[j] == tauhi && p < cnt && (int)idxs[p] <= m);
                }
                c = wave_sumi(c);
                if (c >= nT) h = m; else l = m;
            }
            cut = h;
        }
    }

    uint32_t selm = 0u;
    if (cut == -1) {
        #pragma unroll
        for (int j = 0; j < NSLOT; ++j) selm |= (key[j] > tauhi ? 1u : 0u) << j;
    } else if (cut == 0x7FFFFFFF) {
        #pragma unroll
        for (int j = 0; j < NSLOT; ++j) selm |= (key[j] >= tauhi ? 1u : 0u) << j;
    } else {
        #pragma unroll
        for (int j = 0; j < NSLOT; ++j) {
            int p = lane + j * 64;
            bool sj = (key[j] > tauhi) ||
                      (key[j] == tauhi && p < cnt && (int)idxs[p] <= cut);
            selm |= (sj ? 1u : 0u) << j;
        }
    }

    float St = 0.f, Stt = 0.f, Sts = 0.f, sm = -FLT_MAX;
    #pragma unroll
    for (int j = 0; j < NSLOT; ++j) {
        if (selm & (1u << j)) {
            float tv = keyf(key[j]);
            float e = __expf(tv - tmax);
            St += e; Stt += e * tv; Sts += e * svc[j];
            sm = fmaxf(sm, svc[j]);
        }
    }
    #pragma unroll
    for (int o = 32; o > 0; o >>= 1) {
        St  += __shfl_xor(St,  o, 64);
        Stt += __shfl_xor(Stt, o, 64);
        Sts += __shfl_xor(Sts, o, 64);
        sm = fmaxf(sm, __shfl_xor(sm, o, 64));
    }
    float Ss = 0.f;
    #pragma unroll
    for (int j = 0; j < NSLOT; ++j)
        if (selm & (1u << j)) Ss += __expf(svc[j] - sm);
    Ss = wave_sumf(Ss);
    if (lane == 0)
        return (Stt - Sts) / St - tmax - __logf(St) + sm + __logf(Ss);
    return 0.f;
}

// g0 half (4096 floats): compact (thr filter -> scan -> scatter key+global idx
// to this wave's PRIVATE HCAP segment), then bulk student gather into regs
// (full MLP) and one dense LDS write pass. No barrier needed (own segment).
__device__ int half_compact(const float* __restrict__ tq, const float* __restrict__ sg,
                            float thr, int idx_off,
                            uint32_t* kv, float* sv, uint16_t* ix) {
    const int lane = threadIdx.x & 63;
    const float4* t4 = (const float4*)tq;
    int cnt = 0;
    #pragma unroll
    for (int c0 = 0; c0 < 16; c0 += 8) {
        float4 buf[8];
        #pragma unroll
        for (int u = 0; u < 8; ++u) buf[u] = t4[(c0 + u) * 64 + lane];
        int myc = 0;
        #pragma unroll
        for (int u = 0; u < 8; ++u)
            myc += (buf[u].x > thr) + (buf[u].y > thr) +
                   (buf[u].z > thr) + (buf[u].w > thr);
        int inc = myc;
        #pragma unroll
        for (int o = 1; o < 64; o <<= 1) {
            int y = __shfl_up(inc, o, 64);
            if (lane >= o) inc += y;
        }
        int base = cnt + inc - myc;
        cnt += __shfl(inc, 63, 64);
        #pragma unroll
        for (int u = 0; u < 8; ++u) {
            float xs[4] = {buf[u].x, buf[u].y, buf[u].z, buf[u].w};
            #pragma unroll
            for (int q = 0; q < 4; ++q) {
                if (xs[q] > thr) {
                    if (base < HCAP) {
                        kv[base] = fkey(xs[q]);
                        ix[base] = (uint16_t)(((((c0 + u) * 64 + lane) << 2) + q)
                                              + idx_off);
                    }
                    ++base;
                }
            }
        }
    }
    if (cnt <= HCAP) {
        // pad invalid tail slots (key 0 unselectable: valid keys have sign bit)
        for (int p = cnt + lane; p < HCAP; p += 64) kv[p] = 0u;
        // bulk gather: all loads issued before any LDS write (MLP)
        float r[11];
        #pragma unroll
        for (int j = 0; j < 11; ++j) {
            int p = lane + j * 64;
            r[j] = (p < cnt) ? sg[(int)ix[p]] : 0.f;
        }
        #pragma unroll
        for (int j = 0; j < 11; ++j) {
            int p = lane + j * 64;
            if (p < cnt) sv[p] = r[j];
        }
    }
    return cnt;
}

// Exact top-KSEL + KL over the 2-segment g0 LDS candidate array.
// Falls back to exhaustive scan on overflow. Returns kl on lane 0.
__device__ float pair_select(const uint32_t* __restrict__ kv,
                             const float* __restrict__ sv,
                             const uint16_t* __restrict__ ix,
                             const int* cnts,
                             const float* __restrict__ tg,
                             const float* __restrict__ sg) {
    const int lane = threadIdx.x & 63;
    const int tot = cnts[0] + cnts[1];
    bool bad = (tot < KSEL) || (cnts[0] > HCAP) || (cnts[1] > HCAP);
    if (bad) return wave_slow_kl(tg, sg, 8192);

    uint32_t key[NSEG];
    #pragma unroll
    for (int j = 0; j < NSEG; ++j) key[j] = kv[lane + j * 64];

    uint32_t kmx = 0u, kmn = 0xFFFFFFFFu;
    #pragma unroll
    for (int j = 0; j < NSEG; ++j) {
        uint32_t k = key[j];
        kmx = k > kmx ? k : kmx;
        if (k) kmn = k < kmn ? k : kmn;
    }
    #pragma unroll
    for (int o = 32; o > 0; o >>= 1) {
        uint32_t a = __shfl_xor(kmx, o, 64); kmx = a > kmx ? a : kmx;
        uint32_t b = __shfl_xor(kmn, o, 64); kmn = b < kmn ? b : kmn;
    }
    const float tmax = keyf(kmx);

    uint32_t lo = kmn - 1u, hi = kmx, tauhi = kmx;
    int cl = tot, ch = 0, cut = -1;
    bool exact = false;
    for (int it = 0; it < 80; ++it) {
        uint32_t span = hi - lo;
        if (span <= 1u) break;
        uint32_t mid;
        if (!(it & 1)) {  // false position on empirical CDF
            uint64_t st = (uint64_t)span * (uint32_t)(cl - KSEL) / (uint32_t)(cl - ch);
            if (st < 1) st = 1;
            if (st > span - 1) st = span - 1;
            mid = lo + (uint32_t)st;
        } else mid = lo + (span >> 1);
        int c = 0;
        #pragma unroll
        for (int j = 0; j < NSEG; ++j) c += (key[j] > mid);
        c = wave_sumi(c);
        if (c == KSEL) { tauhi = mid; exact = true; break; }
        if (c > KSEL) { lo = mid; cl = c; } else { hi = mid; ch = c; }
    }
    if (!exact) {
        tauhi = hi;
        const int nT = KSEL - ch, nTie = cl - ch;
        if (nT >= nTie) cut = 0x7FFFFFFF;
        else {  // lowest-global-index tie-break among key==tauhi (rare path)
            int l = -1, h = 8191;
            while (h - l > 1) {
                int m = (l + h) >> 1;
                int c = 0;
                #pragma unroll
                for (int j = 0; j < NSEG; ++j)
                    c += (key[j] == tauhi && (int)ix[lane + j * 64] <= m);
                c = wave_sumi(c);
                if (c >= nT) h = m; else l = m;
            }
            cut = h;
        }
    }

    uint32_t selm = 0u;
    if (cut == -1) {
        #pragma unroll
        for (int j = 0; j < NSEG; ++j) selm |= (key[j] > tauhi ? 1u : 0u) << j;
    } else if (cut == 0x7FFFFFFF) {
        #pragma unroll
        for (int j = 0; j < NSEG; ++j) selm |= (key[j] >= tauhi ? 1u : 0u) << j;
    } else {
        #pragma unroll
        for (int j = 0; j < NSEG; ++j) {
            bool sj = (key[j] > tauhi) ||
                      (key[j] == tauhi && (int)ix[lane + j * 64] <= cut);
            selm |= (sj ? 1u : 0u) << j;
        }
    }

    float St = 0.f, Stt = 0.f, Sts = 0.f, sm = -FLT_MAX;
    #pragma unroll
    for (int j = 0; j < NSEG; ++j) {
        if (selm & (1u << j)) {
            float tv = keyf(key[j]);
            float e = __expf(tv - tmax);
            float s = sv[lane + j * 64];
            St += e; Stt += e * tv; Sts += e * s;
            sm = fmaxf(sm, s);
        }
    }
    #pragma unroll
    for (int o = 32; o > 0; o >>= 1) {
        St  += __shfl_xor(St,  o, 64);
        Stt += __shfl_xor(Stt, o, 64);
        Sts += __shfl_xor(Sts, o, 64);
        sm = fmaxf(sm, __shfl_xor(sm, o, 64));
    }
    float Ss = 0.f;
    #pragma unroll
    for (int j = 0; j < NSEG; ++j)
        if (selm & (1u << j)) Ss += __expf(sv[lane + j * 64] - sm);
    Ss = wave_sumf(Ss);
    if (lane == 0)
        return (Stt - Sts) / St - tmax - __logf(St) + sm + __logf(Ss);
    return 0.f;
}

// Exact top-KSEL + KL on dense register-resident keys (whole group in one wave).
template <int NS, class IdxF>
__device__ float select_accum(uint32_t (&key)[NS], IdxF idxOf, const float* svp) {
    const int lane = threadIdx.x & 63;
    uint32_t kmx = 0u, kmn = 0xFFFFFFFFu;
    #pragma unroll
    for (int j = 0; j < NS; ++j) {
        uint32_t k = key[j];
        kmx = k > kmx ? k : kmx;
        kmn = k < kmn ? k : kmn;
    }
    #pragma unroll
    for (int o = 32; o > 0; o >>= 1) {
        uint32_t a = __shfl_xor(kmx, o, 64); kmx = a > kmx ? a : kmx;
        uint32_t b = __shfl_xor(kmn, o, 64); kmn = b < kmn ? b : kmn;
    }
    const float tmax = keyf(kmx);

    uint32_t lo = kmn - 1u, hi = kmx, tauhi = kmx;
    int cl = NS * 64, ch = 0, cut = -1;
    bool exact = false;
    for (int it = 0; it < 80; ++it) {
        uint32_t span = hi - lo;
        if (span <= 1u) break;
        uint32_t mid;
        if (!(it & 1)) {
            uint64_t st = (uint64_t)span * (uint32_t)(cl - KSEL) / (uint32_t)(cl - ch);
            if (st < 1) st = 1;
            if (st > span - 1) st = span - 1;
            mid = lo + (uint32_t)st;
        } else mid = lo + (span >> 1);
        int c = 0;
        #pragma unroll
        for (int j = 0; j < NS; ++j) c += (key[j] > mid);
        c = wave_sumi(c);
        if (c == KSEL) { tauhi = mid; exact = true; break; }
        if (c > KSEL) { lo = mid; cl = c; } else { hi = mid; ch = c; }
    }
    if (!exact) {
        tauhi = hi;
        const int nT = KSEL - ch, nTie = cl - ch;
        if (nT >= nTie) cut = 0x7FFFFFFF;
        else {
            int l = -1, h = NS * 64 - 1;
            while (h - l > 1) {
                int m = (l + h) >> 1;
                int c = 0;
                #pragma unroll
                for (int j = 0; j < NS; ++j)
                    c += (key[j] == tauhi && idxOf(j) <= m);
                c = wave_sumi(c);
                if (c >= nT) h = m; else l = m;
            }
            cut = h;
        }
    }

    float St = 0.f, Stt = 0.f, Sts = 0.f, sm = -FLT_MAX;
    #pragma unroll
    for (int j = 0; j < NS; ++j) {
        uint32_t kj = key[j];
        bool sj = (kj > tauhi) || (kj == tauhi && idxOf(j) <= cut);
        if (sj) {
            float tv = keyf(kj);
            float e = __expf(tv - tmax);
            St += e; Stt += e * tv; Sts += e * svp[j];
            sm = fmaxf(sm, svp[j]);
        }
    }
    #pragma unroll
    for (int o = 32; o > 0; o >>= 1) {
        St  += __shfl_xor(St,  o, 64);
        Stt += __shfl_xor(Stt, o, 64);
        Sts += __shfl_xor(Sts, o, 64);
        sm = fmaxf(sm, __shfl_xor(sm, o, 64));
    }
    float Ss = 0.f;
    #pragma unroll
    for (int j = 0; j < NS; ++j) {
        uint32_t kj = key[j];
        bool sj = (kj > tauhi) || (kj == tauhi && idxOf(j) <= cut);
        if (sj) Ss += __expf(svp[j] - sm);
    }
    Ss = wave_sumf(Ss);
    if (lane == 0)
        return (Stt - Sts) / St - tmax - __logf(St) + sm + __logf(Ss);
    return 0.f;
}

// mid groups (C = NJ*64): whole group + student prefetched to registers
template <int NJ>
__device__ float mid_wave(const float* __restrict__ t, const float* __restrict__ s) {
    const int lane = threadIdx.x & 63;
    const float4* t4 = (const float4*)t;
    const float4* s4 = (const float4*)s;
    uint32_t key[NJ];
    float svp[NJ];
    #pragma unroll
    for (int c = 0; c < NJ / 4; ++c) {
        float4 x = t4[lane + c * 64];
        float4 y = s4[lane + c * 64];
        key[4 * c + 0] = fkey(x.x); key[4 * c + 1] = fkey(x.y);
        key[4 * c + 2] = fkey(x.z); key[4 * c + 3] = fkey(x.w);
        svp[4 * c + 0] = y.x; svp[4 * c + 1] = y.y;
        svp[4 * c + 2] = y.z; svp[4 * c + 3] = y.w;
    }
    auto idxOf = [&](int j) { return ((lane + (j >> 2) * 64) << 2) + (j & 3); };
    return select_accum<NJ>(key, idxOf, svp);
}

// tiny groups (k == C <= 256): whole-group softmax; returns kl on lane 0
__device__ float tiny_group(const float* __restrict__ t, const float* __restrict__ s,
                            int Cg) {
    const int lane = threadIdx.x & 63;
    float St = 0.f, Stt = 0.f, Sts = 0.f, m = -FLT_MAX, l = 0.f;
    float tv[4], svv[4];
    #pragma unroll
    for (int q = 0; q < 4; ++q) {
        int i = lane + q * 64;
        bool va = i < Cg;
        tv[q] = va ? t[i] : -FLT_MAX;
        svv[q] = va ? s[i] : 0.f;
    }
    float mx = -FLT_MAX;
    #pragma unroll
    for (int q = 0; q < 4; ++q) mx = fmaxf(mx, tv[q]);
    mx = wave_maxf(mx);
    #pragma unroll
    for (int q = 0; q < 4; ++q) {
        if (lane + q * 64 < Cg) {
            float e = __expf(tv[q] - mx);
            St += e; Stt += e * tv[q]; Sts += e * svv[q];
            float x = svv[q];
            if (x > m) { l = l * __expf(m - x) + 1.f; m = x; }
            else       { l += __expf(x - m); }
        }
    }
    #pragma unroll
    for (int o = 32; o > 0; o >>= 1) {
        St  += __shfl_xor(St,  o, 64);
        Stt += __shfl_xor(Stt, o, 64);
        Sts += __shfl_xor(Sts, o, 64);
        float m2 = __shfl_xor(m, o, 64);
        float l2 = __shfl_xor(l, o, 64);
        lse_merge(m, l, m2, l2);
    }
    if (lane == 0)
        return (Stt - Sts) / St - mx - __logf(St) + m + __logf(l);
    return 0.f;
}

// 256 threads = 4 waves. Only g0 (half the row) is split across two waves;
// every other job is self-contained (proven round-0 code). One barrier.
// Pre-barrier bytes: w0 ~31 KB, w1 ~35 KB, w2 ~31 KB, w3 ~32 KB (old max: 62).
// Post-barrier: w0 runs pure-LDS top-500 select for g0.
__global__ __launch_bounds__(256, 4) void kd_all(const float* __restrict__ sL,
                                                 const float* __restrict__ tL,
                                                 float* __restrict__ partial) {
    __shared__ uint32_t kv[2 * HCAP];     // 5.25 KiB  g0 candidate keys
    __shared__ float    sv[2 * HCAP];     // 5.25 KiB  g0 candidate student vals
    __shared__ uint16_t ix[2 * HCAP];     // 2.6 KiB   g0 candidate global idx
    __shared__ int      cnts[2];
    __shared__ float    vals1[CAP];       // 5 KiB     g1 big_wave scratch
    __shared__ uint16_t idxs1[CAP];       // 2.5 KiB

    const int row = blockIdx.x;
    const int w = threadIdx.x >> 6;
    const int lane = threadIdx.x & 63;
    const float* tr = tL + (size_t)row * TOTAL;
    const float* sr = sL + (size_t)row * TOTAL;

    float kl = 0.f;

    switch (w) {
    case 0: {
        int c = half_compact(tr, sr, 1.10f, 0, kv, sv, ix);
        if (lane == 0) cnts[0] = c;
        break;
    }
    case 1: {
        int c = half_compact(tr + 4096, sr, 1.10f, 4096,
                             kv + HCAP, sv + HCAP, ix + HCAP);
        if (lane == 0) cnts[1] = c;
        kl += tiny_group(tr + 15872, sr + 15872, 256);
        kl += tiny_group(tr + 16128, sr + 16128, 128);
        kl += tiny_group(tr + 16256, sr + 16256, 64);
        kl += tiny_group(tr + 16320, sr + 16320, 32);
        kl += tiny_group(tr + 16352, sr + 16352, 16);
        break;
    }
    case 2:
        kl  = big_wave<16>(tr + 8192, sr + 8192, 0.60f, vals1, idxs1);  // g1
        kl += mid_wave<8>(tr + 15360, sr + 15360);                      // g4
        break;
    default:
        kl  = mid_wave<32>(tr + 12288, sr + 12288);   // g2, C=2048
        kl += mid_wave<16>(tr + 14336, sr + 14336);   // g3, C=1024
        break;
    }

    __syncthreads();

    if (w == 0)
        kl += pair_select(kv, sv, ix, cnts, tr, sr);

    if (lane == 0)
        atomicAdd(&partial[(row + w * 37) & (NBUCKET - 1)], kl * (0.1f / 1024.f));
}

__global__ void zero_ws(float* partial) {
    if (threadIdx.x < NBUCKET) partial[threadIdx.x] = 0.f;
}

__global__ void final_sum(const float* __restrict__ partial, float* __restrict__ out) {
    float v = (threadIdx.x < NBUCKET) ? partial[threadIdx.x] : 0.f;
    #pragma unroll
    for (int o = 32; o > 0; o >>= 1) v += __shfl_down(v, o, 64);
    if (threadIdx.x == 0) out[0] = v;
}

extern "C" void kernel_launch(void* const* d_in, const int* in_sizes, int n_in,
                              void* d_out, int out_size, void* d_ws, size_t ws_size,
                              hipStream_t stream) {
    (void)in_sizes; (void)n_in; (void)ws_size; (void)out_size;
    const float* s = (const float*)d_in[0];
    const float* t = (const float*)d_in[1];
    float* out = (float*)d_out;
    float* ws = (float*)d_ws;

    hipLaunchKernelGGL(zero_ws, dim3(1), dim3(64), 0, stream, ws);
    hipLaunchKernelGGL(kd_all, dim3(1024), dim3(256), 0, stream, s, t, ws);
    hipLaunchKernelGGL(final_sum, dim3(1), dim3(64), 0, stream, ws, out);
}

// Round 5
// 171.104 us; speedup vs baseline: 1.1279x; 1.0989x over previous
//
#include <hip/hip_runtime.h>
#include <stdint.h>
#include <float.h>

#define TOTAL 16368
#define KSEL 500
#define CAP 1280          // candidate cap (g0 mean ~1112 +5.4sd; g1 ~1123; g2 ~632)
#define NSLOT 20          // CAP / 64
#define NBUCKET 64

// order-preserving float<->uint key (monotonic increasing on finite floats)
__device__ __forceinline__ uint32_t fkey(float f) {
    uint32_t u = __float_as_uint(f);
    return (u & 0x80000000u) ? ~u : (u | 0x80000000u);
}
__device__ __forceinline__ float keyf(uint32_t k) {
    uint32_t u = (k & 0x80000000u) ? (k & 0x7FFFFFFFu) : ~k;
    return __uint_as_float(u);
}
__device__ __forceinline__ int wave_sumi(int v) {
    #pragma unroll
    for (int o = 32; o > 0; o >>= 1) v += __shfl_xor(v, o, 64);
    return v;
}
__device__ __forceinline__ float wave_sumf(float v) {
    #pragma unroll
    for (int o = 32; o > 0; o >>= 1) v += __shfl_xor(v, o, 64);
    return v;
}
__device__ __forceinline__ float wave_maxf(float v) {
    #pragma unroll
    for (int o = 32; o > 0; o >>= 1) v = fmaxf(v, __shfl_xor(v, o, 64));
    return v;
}
__device__ __forceinline__ void lse_merge(float& m, float& l, float m2, float l2) {
    float M = fmaxf(m, m2);
    l = l * __expf(m - M) + l2 * __expf(m2 - M);
    m = M;
}

// exact exhaustive fallback (never taken for N(0,1) bench data); returns kl on
// lane 0 (0 elsewhere). Bisection on 45-bit key (fkey<<13 | (8191-idx)).
__device__ __noinline__ float wave_slow_kl(const float* __restrict__ t,
                                           const float* __restrict__ s, int C) {
    const int lane = threadIdx.x & 63;
    uint64_t lo = 0ull, hi = (1ull << 45), tau = 0ull;
    int cl = C, ch = 0;
    for (int it = 0; it < 100; ++it) {
        uint64_t span = hi - lo;
        if (span <= 1ull) { tau = lo; break; }
        uint64_t mid;
        if (it & 1) mid = lo + (span >> 1);
        else {
            uint64_t st = span * (uint64_t)(cl - KSEL) / (uint64_t)(cl - ch);
            if (st < 1) st = 1;
            if (st > span - 1) st = span - 1;
            mid = lo + st;
        }
        int c = 0;
        for (int i = lane; i < C; i += 64) {
            uint64_t ck = ((uint64_t)fkey(t[i]) << 13) | (uint64_t)(8191 - i);
            c += (ck > mid);
        }
        c = wave_sumi(c);
        if (c == KSEL) { tau = mid; break; }
        if (c > KSEL) { lo = mid; cl = c; } else { hi = mid; ch = c; }
    }
    float tmx = -FLT_MAX;
    for (int i = lane; i < C; i += 64) tmx = fmaxf(tmx, t[i]);
    tmx = wave_maxf(tmx);
    float St = 0.f, Stt = 0.f, Sts = 0.f, sm = -FLT_MAX;
    for (int i = lane; i < C; i += 64) {
        float x = t[i];
        uint64_t ck = ((uint64_t)fkey(x) << 13) | (uint64_t)(8191 - i);
        if (ck > tau) {
            float e = __expf(x - tmx), v = s[i];
            St += e; Stt += e * x; Sts += e * v;
            sm = fmaxf(sm, v);
        }
    }
    St = wave_sumf(St); Stt = wave_sumf(Stt); Sts = wave_sumf(Sts); sm = wave_maxf(sm);
    float Ss = 0.f;
    for (int i = lane; i < C; i += 64) {
        uint64_t ck = ((uint64_t)fkey(t[i]) << 13) | (uint64_t)(8191 - i);
        if (ck > tau) Ss += __expf(s[i] - sm);
    }
    Ss = wave_sumf(Ss);
    if (lane == 0)
        return (Stt - Sts) / St - tmx - __logf(St) + sm + __logf(Ss);
    return 0.f;
}

// PROVEN round-0 path: big group handled start-to-finish by ONE wave
// (C = NF4*256): stream in 8-float4 bursts; scan-based compaction to LDS;
// keys to regs; EARLY candidate student gather (outstanding across bisection);
// exact bisection + rare LDS-idx tie-break. Returns kl on lane 0.
template <int NF4>
__device__ float big_wave(const float* __restrict__ tg, const float* __restrict__ s,
                          float thr, float* vals, uint16_t* idxs) {
    const int lane = threadIdx.x & 63;
    const float4* t4 = (const float4*)tg;
    int cnt = 0;
    #pragma unroll
    for (int c0 = 0; c0 < NF4; c0 += 8) {
        float4 buf[8];
        #pragma unroll
        for (int u = 0; u < 8; ++u) buf[u] = t4[(c0 + u) * 64 + lane];
        int myc = 0;
        #pragma unroll
        for (int u = 0; u < 8; ++u)
            myc += (buf[u].x > thr) + (buf[u].y > thr) +
                   (buf[u].z > thr) + (buf[u].w > thr);
        int inc = myc;
        #pragma unroll
        for (int o = 1; o < 64; o <<= 1) {
            int y = __shfl_up(inc, o, 64);
            if (lane >= o) inc += y;
        }
        int base = cnt + inc - myc;
        cnt += __shfl(inc, 63, 64);
        #pragma unroll
        for (int u = 0; u < 8; ++u) {
            float xs[4] = {buf[u].x, buf[u].y, buf[u].z, buf[u].w};
            #pragma unroll
            for (int q = 0; q < 4; ++q) {
                if (xs[q] > thr) {
                    if (base < CAP) {
                        vals[base] = xs[q];
                        idxs[base] = (uint16_t)((((c0 + u) * 64 + lane) << 2) + q);
                    }
                    ++base;
                }
            }
        }
    }
    if (cnt < KSEL || cnt > CAP) return wave_slow_kl(tg, s, NF4 * 256);

    // keys to regs + EARLY student gather (vmcnt loads drain under bisection)
    uint32_t key[NSLOT];
    float svc[NSLOT];
    #pragma unroll
    for (int j = 0; j < NSLOT; ++j) {
        int p = lane + j * 64;
        bool v = p < cnt;
        key[j] = v ? fkey(vals[p]) : 0u;
        svc[j] = v ? s[(int)idxs[p]] : 0.f;
    }
    uint32_t kmx = 0u, kmn = 0xFFFFFFFFu;
    #pragma unroll
    for (int j = 0; j < NSLOT; ++j) {
        uint32_t k = key[j];
        kmx = k > kmx ? k : kmx;
        if (k) kmn = k < kmn ? k : kmn;
    }
    #pragma unroll
    for (int o = 32; o > 0; o >>= 1) {
        uint32_t a = __shfl_xor(kmx, o, 64); kmx = a > kmx ? a : kmx;
        uint32_t b = __shfl_xor(kmn, o, 64); kmn = b < kmn ? b : kmn;
    }
    const float tmax = keyf(kmx);

    uint32_t lo = kmn - 1u, hi = kmx, tauhi = kmx;
    int cl = cnt, ch = 0, cut = -1;
    bool exact = false;
    for (int it = 0; it < 80; ++it) {
        uint32_t span = hi - lo;
        if (span <= 1u) break;
        uint32_t mid;
        if (!(it & 1)) {  // false position on empirical CDF
            uint64_t st = (uint64_t)span * (uint32_t)(cl - KSEL) / (uint32_t)(cl - ch);
            if (st < 1) st = 1;
            if (st > span - 1) st = span - 1;
            mid = lo + (uint32_t)st;
        } else mid = lo + (span >> 1);
        int c = 0;
        #pragma unroll
        for (int j = 0; j < NSLOT; ++j) c += (key[j] > mid);
        c = wave_sumi(c);
        if (c == KSEL) { tauhi = mid; exact = true; break; }
        if (c > KSEL) { lo = mid; cl = c; } else { hi = mid; ch = c; }
    }
    if (!exact) {
        tauhi = hi;
        const int nT = KSEL - ch, nTie = cl - ch;
        if (nT >= nTie) cut = 0x7FFFFFFF;
        else {  // lowest-index tie-break; idx re-read from LDS (rare path)
            int l = -1, h = 8191;
            while (h - l > 1) {
                int m = (l + h) >> 1;
                int c = 0;
                #pragma unroll
                for (int j = 0; j < NSLOT; ++j) {
                    int p = lane + j * 64;
                    c += (key[j] == tauhi && p < cnt && (int)idxs[p] <= m);
                }
                c = wave_sumi(c);
                if (c >= nT) h = m; else l = m;
            }
            cut = h;
        }
    }

    uint32_t selm = 0u;
    if (cut == -1) {
        #pragma unroll
        for (int j = 0; j < NSLOT; ++j) selm |= (key[j] > tauhi ? 1u : 0u) << j;
    } else if (cut == 0x7FFFFFFF) {
        #pragma unroll
        for (int j = 0; j < NSLOT; ++j) selm |= (key[j] >= tauhi ? 1u : 0u) << j;
    } else {
        #pragma unroll
        for (int j = 0; j < NSLOT; ++j) {
            int p = lane + j * 64;
            bool sj = (key[j] > tauhi) ||
                      (key[j] == tauhi && p < cnt && (int)idxs[p] <= cut);
            selm |= (sj ? 1u : 0u) << j;
        }
    }

    float St = 0.f, Stt = 0.f, Sts = 0.f, sm = -FLT_MAX;
    #pragma unroll
    for (int j = 0; j < NSLOT; ++j) {
        if (selm & (1u << j)) {
            float tv = keyf(key[j]);
            float e = __expf(tv - tmax);
            St += e; Stt += e * tv; Sts += e * svc[j];
            sm = fmaxf(sm, svc[j]);
        }
    }
    #pragma unroll
    for (int o = 32; o > 0; o >>= 1) {
        St  += __shfl_xor(St,  o, 64);
        Stt += __shfl_xor(Stt, o, 64);
        Sts += __shfl_xor(Sts, o, 64);
        sm = fmaxf(sm, __shfl_xor(sm, o, 64));
    }
    float Ss = 0.f;
    #pragma unroll
    for (int j = 0; j < NSLOT; ++j)
        if (selm & (1u << j)) Ss += __expf(svc[j] - sm);
    Ss = wave_sumf(Ss);
    if (lane == 0)
        return (Stt - Sts) / St - tmax - __logf(St) + sm + __logf(Ss);
    return 0.f;
}

// Exact top-KSEL + KL on dense register-resident keys (whole group in one wave).
template <int NS, class IdxF>
__device__ float select_accum(uint32_t (&key)[NS], IdxF idxOf, const float* svp) {
    const int lane = threadIdx.x & 63;
    uint32_t kmx = 0u, kmn = 0xFFFFFFFFu;
    #pragma unroll
    for (int j = 0; j < NS; ++j) {
        uint32_t k = key[j];
        kmx = k > kmx ? k : kmx;
        kmn = k < kmn ? k : kmn;
    }
    #pragma unroll
    for (int o = 32; o > 0; o >>= 1) {
        uint32_t a = __shfl_xor(kmx, o, 64); kmx = a > kmx ? a : kmx;
        uint32_t b = __shfl_xor(kmn, o, 64); kmn = b < kmn ? b : kmn;
    }
    const float tmax = keyf(kmx);

    uint32_t lo = kmn - 1u, hi = kmx, tauhi = kmx;
    int cl = NS * 64, ch = 0, cut = -1;
    bool exact = false;
    for (int it = 0; it < 80; ++it) {
        uint32_t span = hi - lo;
        if (span <= 1u) break;
        uint32_t mid;
        if (!(it & 1)) {
            uint64_t st = (uint64_t)span * (uint32_t)(cl - KSEL) / (uint32_t)(cl - ch);
            if (st < 1) st = 1;
            if (st > span - 1) st = span - 1;
            mid = lo + (uint32_t)st;
        } else mid = lo + (span >> 1);
        int c = 0;
        #pragma unroll
        for (int j = 0; j < NS; ++j) c += (key[j] > mid);
        c = wave_sumi(c);
        if (c == KSEL) { tauhi = mid; exact = true; break; }
        if (c > KSEL) { lo = mid; cl = c; } else { hi = mid; ch = c; }
    }
    if (!exact) {
        tauhi = hi;
        const int nT = KSEL - ch, nTie = cl - ch;
        if (nT >= nTie) cut = 0x7FFFFFFF;
        else {
            int l = -1, h = NS * 64 - 1;
            while (h - l > 1) {
                int m = (l + h) >> 1;
                int c = 0;
                #pragma unroll
                for (int j = 0; j < NS; ++j)
                    c += (key[j] == tauhi && idxOf(j) <= m);
                c = wave_sumi(c);
                if (c >= nT) h = m; else l = m;
            }
            cut = h;
        }
    }

    float St = 0.f, Stt = 0.f, Sts = 0.f, sm = -FLT_MAX;
    #pragma unroll
    for (int j = 0; j < NS; ++j) {
        uint32_t kj = key[j];
        bool sj = (kj > tauhi) || (kj == tauhi && idxOf(j) <= cut);
        if (sj) {
            float tv = keyf(kj);
            float e = __expf(tv - tmax);
            St += e; Stt += e * tv; Sts += e * svp[j];
            sm = fmaxf(sm, svp[j]);
        }
    }
    #pragma unroll
    for (int o = 32; o > 0; o >>= 1) {
        St  += __shfl_xor(St,  o, 64);
        Stt += __shfl_xor(Stt, o, 64);
        Sts += __shfl_xor(Sts, o, 64);
        sm = fmaxf(sm, __shfl_xor(sm, o, 64));
    }
    float Ss = 0.f;
    #pragma unroll
    for (int j = 0; j < NS; ++j) {
        uint32_t kj = key[j];
        bool sj = (kj > tauhi) || (kj == tauhi && idxOf(j) <= cut);
        if (sj) Ss += __expf(svp[j] - sm);
    }
    Ss = wave_sumf(Ss);
    if (lane == 0)
        return (Stt - Sts) / St - tmax - __logf(St) + sm + __logf(Ss);
    return 0.f;
}

// mid groups (C = NJ*64): whole group + student prefetched to registers
template <int NJ>
__device__ float mid_wave(const float* __restrict__ t, const float* __restrict__ s) {
    const int lane = threadIdx.x & 63;
    const float4* t4 = (const float4*)t;
    const float4* s4 = (const float4*)s;
    uint32_t key[NJ];
    float svp[NJ];
    #pragma unroll
    for (int c = 0; c < NJ / 4; ++c) {
        float4 x = t4[lane + c * 64];
        float4 y = s4[lane + c * 64];
        key[4 * c + 0] = fkey(x.x); key[4 * c + 1] = fkey(x.y);
        key[4 * c + 2] = fkey(x.z); key[4 * c + 3] = fkey(x.w);
        svp[4 * c + 0] = y.x; svp[4 * c + 1] = y.y;
        svp[4 * c + 2] = y.z; svp[4 * c + 3] = y.w;
    }
    auto idxOf = [&](int j) { return ((lane + (j >> 2) * 64) << 2) + (j & 3); };
    return select_accum<NJ>(key, idxOf, svp);
}

// tiny groups (k == C <= 256): whole-group softmax; returns kl on lane 0
__device__ float tiny_group(const float* __restrict__ t, const float* __restrict__ s,
                            int Cg) {
    const int lane = threadIdx.x & 63;
    float St = 0.f, Stt = 0.f, Sts = 0.f, m = -FLT_MAX, l = 0.f;
    float tv[4], svv[4];
    #pragma unroll
    for (int q = 0; q < 4; ++q) {
        int i = lane + q * 64;
        bool va = i < Cg;
        tv[q] = va ? t[i] : -FLT_MAX;
        svv[q] = va ? s[i] : 0.f;
    }
    float mx = -FLT_MAX;
    #pragma unroll
    for (int q = 0; q < 4; ++q) mx = fmaxf(mx, tv[q]);
    mx = wave_maxf(mx);
    #pragma unroll
    for (int q = 0; q < 4; ++q) {
        if (lane + q * 64 < Cg) {
            float e = __expf(tv[q] - mx);
            St += e; Stt += e * tv[q]; Sts += e * svv[q];
            float x = svv[q];
            if (x > m) { l = l * __expf(m - x) + 1.f; m = x; }
            else       { l += __expf(x - m); }
        }
    }
    #pragma unroll
    for (int o = 32; o > 0; o >>= 1) {
        St  += __shfl_xor(St,  o, 64);
        Stt += __shfl_xor(Stt, o, 64);
        Sts += __shfl_xor(Sts, o, 64);
        float m2 = __shfl_xor(m, o, 64);
        float l2 = __shfl_xor(l, o, 64);
        lse_merge(m, l, m2, l2);
    }
    if (lane == 0)
        return (Stt - Sts) / St - mx - __logf(St) + m + __logf(l);
    return 0.f;
}

// ONE WAVE = ONE BLOCK = ONE independent job. 4096 blocks of 64 threads:
//   job 0 (bid 0..1023):    g0  (C=8192, big_wave<32>, thr 1.10)
//   job 1 (bid 1024..2047): g1  (C=4096, big_wave<16>, thr 0.60)
//   job 2 (bid 2048..3071): g2  (C=2048, big_wave<8>,  thr 0.50) + g3 mid_wave<16>
//   job 3 (bid 3072..4095): g4  mid_wave<8> + 5 tiny groups
// No barriers, no intra-block imbalance; the HW scheduler packs heavy and
// light single-wave blocks onto SIMDs (16 waves/CU all resident: LDS 7.7KB
// x16 = 123KB < 160KB), so no lone-wave tail. Heavy jobs dispatch first.
__global__ __launch_bounds__(64, 4) void kd_jobs(const float* __restrict__ sL,
                                                 const float* __restrict__ tL,
                                                 float* __restrict__ partial) {
    __shared__ float    vals[CAP];    // 5 KiB
    __shared__ uint16_t idxs[CAP];    // 2.5 KiB
    const int bid = blockIdx.x;
    const int job = bid >> 10;        // heavy jobs first in dispatch order
    const int row = bid & 1023;
    const float* tr = tL + (size_t)row * TOTAL;
    const float* sr = sL + (size_t)row * TOTAL;

    float kl = 0.f;
    switch (job) {
    case 0:
        kl = big_wave<32>(tr, sr, 1.10f, vals, idxs);
        break;
    case 1:
        kl = big_wave<16>(tr + 8192, sr + 8192, 0.60f, vals, idxs);
        break;
    case 2:
        kl  = big_wave<8>(tr + 12288, sr + 12288, 0.50f, vals, idxs);  // g2
        kl += mid_wave<16>(tr + 14336, sr + 14336);                    // g3
        break;
    default:
        kl  = mid_wave<8>(tr + 15360, sr + 15360);                     // g4
        kl += tiny_group(tr + 15872, sr + 15872, 256);
        kl += tiny_group(tr + 16128, sr + 16128, 128);
        kl += tiny_group(tr + 16256, sr + 16256, 64);
        kl += tiny_group(tr + 16320, sr + 16320, 32);
        kl += tiny_group(tr + 16352, sr + 16352, 16);
        break;
    }

    if ((threadIdx.x & 63) == 0)
        atomicAdd(&partial[(row + job * 37) & (NBUCKET - 1)], kl * (0.1f / 1024.f));
}

__global__ void zero_ws(float* partial) {
    if (threadIdx.x < NBUCKET) partial[threadIdx.x] = 0.f;
}

__global__ void final_sum(const float* __restrict__ partial, float* __restrict__ out) {
    float v = (threadIdx.x < NBUCKET) ? partial[threadIdx.x] : 0.f;
    #pragma unroll
    for (int o = 32; o > 0; o >>= 1) v += __shfl_down(v, o, 64);
    if (threadIdx.x == 0) out[0] = v;
}

extern "C" void kernel_launch(void* const* d_in, const int* in_sizes, int n_in,
                              void* d_out, int out_size, void* d_ws, size_t ws_size,
                              hipStream_t stream) {
    (void)in_sizes; (void)n_in; (void)ws_size; (void)out_size;
    const float* s = (const float*)d_in[0];
    const float* t = (const float*)d_in[1];
    float* out = (float*)d_out;
    float* ws = (float*)d_ws;

    hipLaunchKernelGGL(zero_ws, dim3(1), dim3(64), 0, stream, ws);
    hipLaunchKernelGGL(kd_jobs, dim3(4096), dim3(64), 0, stream, s, t, ws);
    hipLaunchKernelGGL(final_sum, dim3(1), dim3(64), 0, stream, ws, out);
}

// Round 6
// 167.392 us; speedup vs baseline: 1.1529x; 1.0222x over previous
//
#include <hip/hip_runtime.h>
#include <stdint.h>
#include <float.h>

#define TOTAL 16368
#define KSEL 500
#define CAP 1280          // candidate cap (g0 mean ~1112 +5.4sd; g1 ~1123; g2 ~632)
#define NSLOT 20          // CAP / 64
#define NBUCKET 64

// order-preserving float<->uint key (monotonic increasing on finite floats)
__device__ __forceinline__ uint32_t fkey(float f) {
    uint32_t u = __float_as_uint(f);
    return (u & 0x80000000u) ? ~u : (u | 0x80000000u);
}
__device__ __forceinline__ float keyf(uint32_t k) {
    uint32_t u = (k & 0x80000000u) ? (k & 0x7FFFFFFFu) : ~k;
    return __uint_as_float(u);
}
// exclusive rank of this lane within ballot mask m (lanes below me that are set)
__device__ __forceinline__ int lanerank(uint64_t m) {
    return __builtin_amdgcn_mbcnt_hi((uint32_t)(m >> 32),
           __builtin_amdgcn_mbcnt_lo((uint32_t)m, 0));
}
__device__ __forceinline__ int wave_sumi(int v) {
    #pragma unroll
    for (int o = 32; o > 0; o >>= 1) v += __shfl_xor(v, o, 64);
    return v;
}
__device__ __forceinline__ float wave_sumf(float v) {
    #pragma unroll
    for (int o = 32; o > 0; o >>= 1) v += __shfl_xor(v, o, 64);
    return v;
}
__device__ __forceinline__ float wave_maxf(float v) {
    #pragma unroll
    for (int o = 32; o > 0; o >>= 1) v = fmaxf(v, __shfl_xor(v, o, 64));
    return v;
}
__device__ __forceinline__ void lse_merge(float& m, float& l, float m2, float l2) {
    float M = fmaxf(m, m2);
    l = l * __expf(m - M) + l2 * __expf(m2 - M);
    m = M;
}

// exact exhaustive fallback (never taken for N(0,1) bench data); returns kl on
// lane 0 (0 elsewhere). Bisection on 45-bit key (fkey<<13 | (8191-idx)).
__device__ __noinline__ float wave_slow_kl(const float* __restrict__ t,
                                           const float* __restrict__ s, int C) {
    const int lane = threadIdx.x & 63;
    uint64_t lo = 0ull, hi = (1ull << 45), tau = 0ull;
    int cl = C, ch = 0;
    #pragma unroll 1
    for (int it = 0; it < 100; ++it) {
        uint64_t span = hi - lo;
        if (span <= 1ull) { tau = lo; break; }
        uint64_t mid;
        if (it & 1) mid = lo + (span >> 1);
        else {
            uint64_t st = span * (uint64_t)(cl - KSEL) / (uint64_t)(cl - ch);
            if (st < 1) st = 1;
            if (st > span - 1) st = span - 1;
            mid = lo + st;
        }
        int c = 0;
        #pragma unroll 1
        for (int i = lane; i < C; i += 64) {
            uint64_t ck = ((uint64_t)fkey(t[i]) << 13) | (uint64_t)(8191 - i);
            c += (ck > mid);
        }
        c = wave_sumi(c);
        if (c == KSEL) { tau = mid; break; }
        if (c > KSEL) { lo = mid; cl = c; } else { hi = mid; ch = c; }
    }
    float tmx = -FLT_MAX;
    for (int i = lane; i < C; i += 64) tmx = fmaxf(tmx, t[i]);
    tmx = wave_maxf(tmx);
    float St = 0.f, Stt = 0.f, Sts = 0.f, sm = -FLT_MAX;
    #pragma unroll 1
    for (int i = lane; i < C; i += 64) {
        float x = t[i];
        uint64_t ck = ((uint64_t)fkey(x) << 13) | (uint64_t)(8191 - i);
        if (ck > tau) {
            float e = __expf(x - tmx), v = s[i];
            St += e; Stt += e * x; Sts += e * v;
            sm = fmaxf(sm, v);
        }
    }
    St = wave_sumf(St); Stt = wave_sumf(Stt); Sts = wave_sumf(Sts); sm = wave_maxf(sm);
    float Ss = 0.f;
    #pragma unroll 1
    for (int i = lane; i < C; i += 64) {
        uint64_t ck = ((uint64_t)fkey(t[i]) << 13) | (uint64_t)(8191 - i);
        if (ck > tau) Ss += __expf(s[i] - sm);
    }
    Ss = wave_sumf(Ss);
    if (lane == 0)
        return (Stt - Sts) / St - tmx - __logf(St) + sm + __logf(Ss);
    return 0.f;
}

// Big group start-to-finish in ONE wave (C = NF4*256), BALLOT edition:
// compaction via per-element ballot+mbcnt (no bpermute scans, scalar cnt);
// double-buffered 8-float4 bursts (next burst's loads in flight under the
// current burst's processing); bisection counts via ballot+s_bcnt1 (scalar,
// no shfl chains). Candidate array order differs from the scan version but
// selection depends only on (key, global idx) VALUES, not positions.
template <int NF4>
__device__ float big_wave(const float* __restrict__ tg, const float* __restrict__ s,
                          float thr, float* vals, uint16_t* idxs) {
    const int lane = threadIdx.x & 63;
    const float4* t4 = (const float4*)tg;
    constexpr int NB = NF4 / 8;
    int cnt = 0;
    float4 buf[8], nxt[8];
    #pragma unroll
    for (int u = 0; u < 8; ++u) buf[u] = t4[u * 64 + lane];
    #pragma unroll 1
    for (int b = 0; b < NB; ++b) {
        if (b + 1 < NB) {
            #pragma unroll
            for (int u = 0; u < 8; ++u)
                nxt[u] = t4[((b + 1) * 8 + u) * 64 + lane];
        }
        #pragma unroll
        for (int u = 0; u < 8; ++u) {
            float xs[4] = {buf[u].x, buf[u].y, buf[u].z, buf[u].w};
            #pragma unroll
            for (int q = 0; q < 4; ++q) {
                bool p = xs[q] > thr;
                uint64_t m = __ballot(p);
                if (p) {
                    int ofs = cnt + lanerank(m);
                    if (ofs < CAP) {
                        vals[ofs] = xs[q];
                        idxs[ofs] = (uint16_t)((((b * 8 + u) * 64 + lane) << 2) + q);
                    }
                }
                cnt += (int)__popcll(m);
            }
        }
        if (b + 1 < NB) {
            #pragma unroll
            for (int u = 0; u < 8; ++u) buf[u] = nxt[u];
        }
    }
    if (cnt < KSEL || cnt > CAP) return wave_slow_kl(tg, s, NF4 * 256);

    // keys to regs + EARLY student gather (vmcnt loads drain under bisection)
    uint32_t key[NSLOT];
    float svc[NSLOT];
    #pragma unroll
    for (int j = 0; j < NSLOT; ++j) {
        int p = lane + j * 64;
        bool v = p < cnt;
        key[j] = v ? fkey(vals[p]) : 0u;
        svc[j] = v ? s[(int)idxs[p]] : 0.f;
    }
    uint32_t kmx = 0u, kmn = 0xFFFFFFFFu;
    #pragma unroll
    for (int j = 0; j < NSLOT; ++j) {
        uint32_t k = key[j];
        kmx = k > kmx ? k : kmx;
        if (k) kmn = k < kmn ? k : kmn;
    }
    #pragma unroll
    for (int o = 32; o > 0; o >>= 1) {
        uint32_t a = __shfl_xor(kmx, o, 64); kmx = a > kmx ? a : kmx;
        uint32_t b2 = __shfl_xor(kmn, o, 64); kmn = b2 < kmn ? b2 : kmn;
    }
    const float tmax = keyf(kmx);

    uint32_t lo = kmn - 1u, hi = kmx, tauhi = kmx;
    int cl = cnt, ch = 0, cut = -1;
    bool exact = false;
    #pragma unroll 1
    for (int it = 0; it < 80; ++it) {
        uint32_t span = hi - lo;
        if (span <= 1u) break;
        uint32_t mid;
        if (!(it & 1)) {  // false position on empirical CDF
            uint64_t st = (uint64_t)span * (uint32_t)(cl - KSEL) / (uint32_t)(cl - ch);
            if (st < 1) st = 1;
            if (st > span - 1) st = span - 1;
            mid = lo + (uint32_t)st;
        } else mid = lo + (span >> 1);
        int c = 0;
        #pragma unroll
        for (int j = 0; j < NSLOT; ++j)
            c += (int)__popcll(__ballot(key[j] > mid));
        if (c == KSEL) { tauhi = mid; exact = true; break; }
        if (c > KSEL) { lo = mid; cl = c; } else { hi = mid; ch = c; }
    }
    if (!exact) {
        tauhi = hi;
        const int nT = KSEL - ch, nTie = cl - ch;
        if (nT >= nTie) cut = 0x7FFFFFFF;
        else {  // lowest-index tie-break; idx hoisted to regs (rare path)
            int idxr[NSLOT];
            #pragma unroll
            for (int j = 0; j < NSLOT; ++j) {
                int p = lane + j * 64;
                idxr[j] = (p < cnt) ? (int)idxs[p] : 0x7FFF;
            }
            int l = -1, h = 8191;
            #pragma unroll 1
            while (h - l > 1) {
                int m = (l + h) >> 1;
                int c = 0;
                #pragma unroll
                for (int j = 0; j < NSLOT; ++j)
                    c += (int)__popcll(__ballot(key[j] == tauhi && idxr[j] <= m));
                if (c >= nT) h = m; else l = m;
            }
            cut = h;
        }
    }

    uint32_t selm = 0u;
    if (cut == -1) {
        #pragma unroll
        for (int j = 0; j < NSLOT; ++j) selm |= (key[j] > tauhi ? 1u : 0u) << j;
    } else if (cut == 0x7FFFFFFF) {
        #pragma unroll
        for (int j = 0; j < NSLOT; ++j) selm |= (key[j] >= tauhi ? 1u : 0u) << j;
    } else {
        #pragma unroll
        for (int j = 0; j < NSLOT; ++j) {
            int p = lane + j * 64;
            bool sj = (key[j] > tauhi) ||
                      (key[j] == tauhi && p < cnt && (int)idxs[p] <= cut);
            selm |= (sj ? 1u : 0u) << j;
        }
    }

    float St = 0.f, Stt = 0.f, Sts = 0.f, sm = -FLT_MAX;
    #pragma unroll
    for (int j = 0; j < NSLOT; ++j) {
        if (selm & (1u << j)) {
            float tv = keyf(key[j]);
            float e = __expf(tv - tmax);
            St += e; Stt += e * tv; Sts += e * svc[j];
            sm = fmaxf(sm, svc[j]);
        }
    }
    #pragma unroll
    for (int o = 32; o > 0; o >>= 1) {
        St  += __shfl_xor(St,  o, 64);
        Stt += __shfl_xor(Stt, o, 64);
        Sts += __shfl_xor(Sts, o, 64);
        sm = fmaxf(sm, __shfl_xor(sm, o, 64));
    }
    float Ss = 0.f;
    #pragma unroll
    for (int j = 0; j < NSLOT; ++j)
        if (selm & (1u << j)) Ss += __expf(svc[j] - sm);
    Ss = wave_sumf(Ss);
    if (lane == 0)
        return (Stt - Sts) / St - tmax - __logf(St) + sm + __logf(Ss);
    return 0.f;
}

// Exact top-KSEL + KL on dense register-resident keys, BALLOT bisection.
template <int NS, class IdxF>
__device__ float select_accum(uint32_t (&key)[NS], IdxF idxOf, const float* svp) {
    const int lane = threadIdx.x & 63;
    uint32_t kmx = 0u, kmn = 0xFFFFFFFFu;
    #pragma unroll
    for (int j = 0; j < NS; ++j) {
        uint32_t k = key[j];
        kmx = k > kmx ? k : kmx;
        kmn = k < kmn ? k : kmn;
    }
    #pragma unroll
    for (int o = 32; o > 0; o >>= 1) {
        uint32_t a = __shfl_xor(kmx, o, 64); kmx = a > kmx ? a : kmx;
        uint32_t b = __shfl_xor(kmn, o, 64); kmn = b < kmn ? b : kmn;
    }
    const float tmax = keyf(kmx);

    uint32_t lo = kmn - 1u, hi = kmx, tauhi = kmx;
    int cl = NS * 64, ch = 0, cut = -1;
    bool exact = false;
    #pragma unroll 1
    for (int it = 0; it < 80; ++it) {
        uint32_t span = hi - lo;
        if (span <= 1u) break;
        uint32_t mid;
        if (!(it & 1)) {
            uint64_t st = (uint64_t)span * (uint32_t)(cl - KSEL) / (uint32_t)(cl - ch);
            if (st < 1) st = 1;
            if (st > span - 1) st = span - 1;
            mid = lo + (uint32_t)st;
        } else mid = lo + (span >> 1);
        int c = 0;
        #pragma unroll
        for (int j = 0; j < NS; ++j)
            c += (int)__popcll(__ballot(key[j] > mid));
        if (c == KSEL) { tauhi = mid; exact = true; break; }
        if (c > KSEL) { lo = mid; cl = c; } else { hi = mid; ch = c; }
    }
    if (!exact) {
        tauhi = hi;
        const int nT = KSEL - ch, nTie = cl - ch;
        if (nT >= nTie) cut = 0x7FFFFFFF;
        else {
            int l = -1, h = NS * 64 - 1;
            #pragma unroll 1
            while (h - l > 1) {
                int m = (l + h) >> 1;
                int c = 0;
                #pragma unroll
                for (int j = 0; j < NS; ++j)
                    c += (int)__popcll(__ballot(key[j] == tauhi && idxOf(j) <= m));
                if (c >= nT) h = m; else l = m;
            }
            cut = h;
        }
    }

    float St = 0.f, Stt = 0.f, Sts = 0.f, sm = -FLT_MAX;
    #pragma unroll
    for (int j = 0; j < NS; ++j) {
        uint32_t kj = key[j];
        bool sj = (kj > tauhi) || (kj == tauhi && idxOf(j) <= cut);
        if (sj) {
            float tv = keyf(kj);
            float e = __expf(tv - tmax);
            St += e; Stt += e * tv; Sts += e * svp[j];
            sm = fmaxf(sm, svp[j]);
        }
    }
    #pragma unroll
    for (int o = 32; o > 0; o >>= 1) {
        St  += __shfl_xor(St,  o, 64);
        Stt += __shfl_xor(Stt, o, 64);
        Sts += __shfl_xor(Sts, o, 64);
        sm = fmaxf(sm, __shfl_xor(sm, o, 64));
    }
    float Ss = 0.f;
    #pragma unroll
    for (int j = 0; j < NS; ++j) {
        uint32_t kj = key[j];
        bool sj = (kj > tauhi) || (kj == tauhi && idxOf(j) <= cut);
        if (sj) Ss += __expf(svp[j] - sm);
    }
    Ss = wave_sumf(Ss);
    if (lane == 0)
        return (Stt - Sts) / St - tmax - __logf(St) + sm + __logf(Ss);
    return 0.f;
}

// mid groups (C = NJ*64): whole group + student prefetched to registers
template <int NJ>
__device__ float mid_wave(const float* __restrict__ t, const float* __restrict__ s) {
    const int lane = threadIdx.x & 63;
    const float4* t4 = (const float4*)t;
    const float4* s4 = (const float4*)s;
    uint32_t key[NJ];
    float svp[NJ];
    #pragma unroll
    for (int c = 0; c < NJ / 4; ++c) {
        float4 x = t4[lane + c * 64];
        float4 y = s4[lane + c * 64];
        key[4 * c + 0] = fkey(x.x); key[4 * c + 1] = fkey(x.y);
        key[4 * c + 2] = fkey(x.z); key[4 * c + 3] = fkey(x.w);
        svp[4 * c + 0] = y.x; svp[4 * c + 1] = y.y;
        svp[4 * c + 2] = y.z; svp[4 * c + 3] = y.w;
    }
    auto idxOf = [&](int j) { return ((lane + (j >> 2) * 64) << 2) + (j & 3); };
    return select_accum<NJ>(key, idxOf, svp);
}

// tiny groups (k == C <= 256): whole-group softmax; returns kl on lane 0
__device__ float tiny_group(const float* __restrict__ t, const float* __restrict__ s,
                            int Cg) {
    const int lane = threadIdx.x & 63;
    float St = 0.f, Stt = 0.f, Sts = 0.f, m = -FLT_MAX, l = 0.f;
    float tv[4], svv[4];
    #pragma unroll
    for (int q = 0; q < 4; ++q) {
        int i = lane + q * 64;
        bool va = i < Cg;
        tv[q] = va ? t[i] : -FLT_MAX;
        svv[q] = va ? s[i] : 0.f;
    }
    float mx = -FLT_MAX;
    #pragma unroll
    for (int q = 0; q < 4; ++q) mx = fmaxf(mx, tv[q]);
    mx = wave_maxf(mx);
    #pragma unroll
    for (int q = 0; q < 4; ++q) {
        if (lane + q * 64 < Cg) {
            float e = __expf(tv[q] - mx);
            St += e; Stt += e * tv[q]; Sts += e * svv[q];
            float x = svv[q];
            if (x > m) { l = l * __expf(m - x) + 1.f; m = x; }
            else       { l += __expf(x - m); }
        }
    }
    #pragma unroll
    for (int o = 32; o > 0; o >>= 1) {
        St  += __shfl_xor(St,  o, 64);
        Stt += __shfl_xor(Stt, o, 64);
        Sts += __shfl_xor(Sts, o, 64);
        float m2 = __shfl_xor(m, o, 64);
        float l2 = __shfl_xor(l, o, 64);
        lse_merge(m, l, m2, l2);
    }
    if (lane == 0)
        return (Stt - Sts) / St - mx - __logf(St) + m + __logf(l);
    return 0.f;
}

// ONE WAVE = ONE BLOCK = ONE independent job (structure identical to R5):
//   job 0: g0 (8192)   job 1: g1 (4096)   job 2: g2 (2048) + g3 (1024)
//   job 3: g4 (512) + tinies. No barriers; heavy jobs dispatch first.
__global__ __launch_bounds__(64, 4) void kd_jobs(const float* __restrict__ sL,
                                                 const float* __restrict__ tL,
                                                 float* __restrict__ partial) {
    __shared__ float    vals[CAP];    // 5 KiB
    __shared__ uint16_t idxs[CAP];    // 2.5 KiB
    const int bid = blockIdx.x;
    const int job = bid >> 10;
    const int row = bid & 1023;
    const float* tr = tL + (size_t)row * TOTAL;
    const float* sr = sL + (size_t)row * TOTAL;

    float kl = 0.f;
    switch (job) {
    case 0:
        kl = big_wave<32>(tr, sr, 1.10f, vals, idxs);
        break;
    case 1:
        kl = big_wave<16>(tr + 8192, sr + 8192, 0.60f, vals, idxs);
        break;
    case 2:
        kl  = big_wave<8>(tr + 12288, sr + 12288, 0.50f, vals, idxs);  // g2
        kl += mid_wave<16>(tr + 14336, sr + 14336);                    // g3
        break;
    default:
        kl  = mid_wave<8>(tr + 15360, sr + 15360);                     // g4
        kl += tiny_group(tr + 15872, sr + 15872, 256);
        kl += tiny_group(tr + 16128, sr + 16128, 128);
        kl += tiny_group(tr + 16256, sr + 16256, 64);
        kl += tiny_group(tr + 16320, sr + 16320, 32);
        kl += tiny_group(tr + 16352, sr + 16352, 16);
        break;
    }

    if ((threadIdx.x & 63) == 0)
        atomicAdd(&partial[(row + job * 37) & (NBUCKET - 1)], kl * (0.1f / 1024.f));
}

__global__ void zero_ws(float* partial) {
    if (threadIdx.x < NBUCKET) partial[threadIdx.x] = 0.f;
}

__global__ void final_sum(const float* __restrict__ partial, float* __restrict__ out) {
    float v = (threadIdx.x < NBUCKET) ? partial[threadIdx.x] : 0.f;
    #pragma unroll
    for (int o = 32; o > 0; o >>= 1) v += __shfl_down(v, o, 64);
    if (threadIdx.x == 0) out[0] = v;
}

extern "C" void kernel_launch(void* const* d_in, const int* in_sizes, int n_in,
                              void* d_out, int out_size, void* d_ws, size_t ws_size,
                              hipStream_t stream) {
    (void)in_sizes; (void)n_in; (void)ws_size; (void)out_size;
    const float* s = (const float*)d_in[0];
    const float* t = (const float*)d_in[1];
    float* out = (float*)d_out;
    float* ws = (float*)d_ws;

    hipLaunchKernelGGL(zero_ws, dim3(1), dim3(64), 0, stream, ws);
    hipLaunchKernelGGL(kd_jobs, dim3(4096), dim3(64), 0, stream, s, t, ws);
    hipLaunchKernelGGL(final_sum, dim3(1), dim3(64), 0, stream, ws, out);
}